// Round 8
// baseline (469.407 us; speedup 1.0000x reference)
//
#include <hip/hip_runtime.h>
#include <hip/hip_fp16.h>
#include <math.h>

#define B_ 2
#define N_ 6400
#define E_ 256
#define C_ 6
#define L_ 4
#define SL2_ 128  // 2-channel slices (E/2)
#define CH_ 2     // camera halves (3 cams each)

// Level geometry (H, W), flattened per-channel offsets, total pixels/channel
__device__ __host__ constexpr int HWH[4] = {64, 32, 16, 8};
__device__ __host__ constexpr int HWW[4] = {176, 88, 44, 22};
__device__ __host__ constexpr int LOFF[4] = {0, 11264, 14080, 14784};
#define HWT 14960

typedef __attribute__((ext_vector_type(8))) _Float16 half8;
typedef __attribute__((ext_vector_type(4))) float floatx4;

// ---------------------------------------------------------------------------
// Kernel 1: per-point prep. (unchanged)
// ---------------------------------------------------------------------------
__global__ __launch_bounds__(256) void prep_kernel(
    const float* __restrict__ inst, const float* __restrict__ anchor,
    const float* __restrict__ proj, const float* __restrict__ attn_w,
    const float* __restrict__ attn_b,
    uint4* __restrict__ meta_w, int4* __restrict__ meta_b)
{
    __shared__ float AWT[256 * 24];   // attn_w transposed [k][j]
    __shared__ float ts[256 * 33];    // inst tile [point][k-chunk], padded

    const int tid = threadIdx.x;

    for (int idx = tid; idx < 24 * 256; idx += 256) {
        int j = idx >> 8, k = idx & 255;
        AWT[k * 24 + j] = attn_w[idx];
    }
    __syncthreads();

    const int pt0 = blockIdx.x * 256;

    float acc[24];
#pragma unroll
    for (int j = 0; j < 24; j++) acc[j] = attn_b[j];

    for (int k0 = 0; k0 < 256; k0 += 32) {
#pragma unroll
        for (int r = 0; r < 32; r++) {
            int lin = r * 256 + tid;
            int p = lin >> 5, kk = lin & 31;
            ts[p * 33 + kk] = inst[(size_t)(pt0 + p) * 256 + k0 + kk];
        }
        __syncthreads();
#pragma unroll
        for (int kk = 0; kk < 32; kk++) {
            float v = ts[tid * 33 + kk];
            const float* aw = &AWT[(k0 + kk) * 24];
#pragma unroll
            for (int j = 0; j < 24; j++) acc[j] += v * aw[j];
        }
        __syncthreads();
    }

    const int pt = pt0 + tid;
    const int b = pt / N_;   // uniform per block (6400 % 256 == 0)
    const int n = pt - b * N_;

    float attn[24];
#pragma unroll
    for (int c = 0; c < C_; c++) {
        float m = fmaxf(fmaxf(acc[c * 4], acc[c * 4 + 1]),
                        fmaxf(acc[c * 4 + 2], acc[c * 4 + 3]));
        float s = 0.f;
#pragma unroll
        for (int l = 0; l < L_; l++) {
            float e = expf(acc[c * 4 + l] - m);
            attn[c * 4 + l] = e;
            s += e;
        }
        float r = 1.f / s;
#pragma unroll
        for (int l = 0; l < L_; l++) attn[c * 4 + l] *= r;
    }

    float ax = anchor[(size_t)pt * 11 + 0];
    float ay = anchor[(size_t)pt * 11 + 1];
    float az = anchor[(size_t)pt * 11 + 2];
    float wxp = (1.f / (1.f + expf(-ax))) * 102.4f - 51.2f;
    float wyp = (1.f / (1.f + expf(-ay))) * 102.4f - 51.2f;
    float wzp = (1.f / (1.f + expf(-az))) * 8.f - 5.f;

#pragma unroll
    for (int c = 0; c < C_; c++) {
        const float* P = &proj[(size_t)(b * C_ + c) * 16];
        float cx = P[0] * wxp + P[1] * wyp + P[2] * wzp + P[3];
        float cy = P[4] * wxp + P[5] * wyp + P[6] * wzp + P[7];
        float cz = P[8] * wxp + P[9] * wyp + P[10] * wzp + P[11];
        float d = fmaxf(cz, 1e-4f);
        float u = cx / d, v = cy / d;

        float x0f = floorf(u), y0f = floorf(v);
        float fx1 = u - x0f, fy1 = v - y0f;
        float fx0 = 1.f - fx1, fy0 = 1.f - fy1;

        float4 wl[4]; int bsx[4];
#pragma unroll
        for (int l = 0; l < L_; l++) {
            const int W = HWW[l], H = HWH[l];
            float ax0, ax1; int bx;
            int ix = (int)fminf(fmaxf(x0f, -2.f), (float)W);
            if (ix <= -2 || ix >= W)      { ax0 = 0.f;  ax1 = 0.f;  bx = 0; }
            else if (ix == -1)            { ax0 = fx1;  ax1 = 0.f;  bx = 0; }
            else if (ix == W - 1)         { ax0 = 0.f;  ax1 = fx0;  bx = W - 2; }
            else                          { ax0 = fx0;  ax1 = fx1;  bx = ix; }
            float ay0, ay1; int by;
            int iy = (int)fminf(fmaxf(y0f, -2.f), (float)H);
            if (iy <= -2 || iy >= H)      { ay0 = 0.f;  ay1 = 0.f;  by = 0; }
            else if (iy == -1)            { ay0 = fy1;  ay1 = 0.f;  by = 0; }
            else if (iy == H - 1)         { ay0 = 0.f;  ay1 = fy0;  by = H - 2; }
            else                          { ay0 = fy0;  ay1 = fy1;  by = iy; }

            float a = attn[c * 4 + l];
            wl[l] = make_float4(a * ay0 * ax0, a * ay0 * ax1,
                                a * ay1 * ax0, a * ay1 * ax1);
            bsx[l] = by * W + bx;
        }
        size_t mi = (size_t)(b * C_ + c) * N_ + n;
        union { uint4 u; __half2 h[4]; } q0, q1;
        q0.h[0] = __floats2half2_rn(wl[0].x, wl[0].y);
        q0.h[1] = __floats2half2_rn(wl[0].z, wl[0].w);
        q0.h[2] = __floats2half2_rn(wl[1].x, wl[1].y);
        q0.h[3] = __floats2half2_rn(wl[1].z, wl[1].w);
        q1.h[0] = __floats2half2_rn(wl[2].x, wl[2].y);
        q1.h[1] = __floats2half2_rn(wl[2].z, wl[2].w);
        q1.h[2] = __floats2half2_rn(wl[3].x, wl[3].y);
        q1.h[3] = __floats2half2_rn(wl[3].z, wl[3].w);
        meta_w[mi * 2 + 0] = q0.u;
        meta_w[mi * 2 + 1] = q1.u;
        meta_b[mi] = make_int4(bsx[0], bsx[1], bsx[2], bsx[3]);
    }
}

// ---------------------------------------------------------------------------
// Kernel 2 (main path): gather with in-register 3-camera reduction.
// Block = (b, cam-half, 2-channel slice); grid 512. Loops 3 cams: stage cam's
// 2 channel planes fp16 into LDS (same total staged bytes as before: 512x3x
// 120KB = 184 MB), fp16 packed point loop accumulates into 7 per-thread
// half2 registers ACROSS cams; one summed store at the end. part2 shrinks
// 39.3 -> 13.1 MB (written once, read once by gemm which now reduces 2
// halves instead of 6 cams).
// part2 layout: __half2[((b*CH+h)*SL2 + slice)*N + n].
// ---------------------------------------------------------------------------
__global__ __launch_bounds__(1024) void gather3(
    const float* __restrict__ f0, const float* __restrict__ f1,
    const float* __restrict__ f2, const float* __restrict__ f3,
    const uint4* __restrict__ meta_w, const int4* __restrict__ meta_b,
    __half2* __restrict__ part2)
{
    __shared__ __half2 lds2[HWT];   // 59840 B -> 2 blocks/CU

    const int tid = threadIdx.x;
    const int bid = blockIdx.x;               // grid = B_*CH_*SL2_ = 512
    const int slice = bid & 127;
    const int chalf = (bid >> 7) & 1;
    const int b = bid >> 8;
    const int e0 = slice * 2;

    const float* fs[4] = {f0, f1, f2, f3};

    __half2 acc[7];
#pragma unroll
    for (int k = 0; k < 7; k++) acc[k] = __float2half2_rn(0.f);

    for (int cc = 0; cc < 3; cc++) {
        const int c = chalf * 3 + cc;
        const int bc = b * C_ + c;

        if (cc) __syncthreads();   // prior point-loop reads done before restage

#pragma unroll
        for (int l = 0; l < L_; l++) {
            const int HW = HWH[l] * HWW[l];
            const float* s0 = fs[l] + (size_t)(bc * E_ + e0) * HW;
            const float* s1 = s0 + HW;
            const int quarter = HW >> 2;
            for (int q = tid; q < quarter; q += 1024) {
                int p = q * 4;
                float4 v0 = *(const float4*)(s0 + p);
                float4 v1 = *(const float4*)(s1 + p);
                union { uint4 u; __half2 h[4]; } pk;
                pk.h[0] = __floats2half2_rn(v0.x, v1.x);
                pk.h[1] = __floats2half2_rn(v0.y, v1.y);
                pk.h[2] = __floats2half2_rn(v0.z, v1.z);
                pk.h[3] = __floats2half2_rn(v0.w, v1.w);
                *(uint4*)&lds2[LOFF[l] + p] = pk.u;
            }
        }
        __syncthreads();

        const uint4* mwp = meta_w + (size_t)bc * N_ * 2;
        const int4* mbp = meta_b + (size_t)bc * N_;

        uint4 m0 = mwp[(size_t)tid * 2];
        uint4 m1 = mwp[(size_t)tid * 2 + 1];
        int4 px = mbp[tid];

#pragma unroll
        for (int k = 0; k < 7; k++) {
            uint4 q0, q1; int4 qx;          // prefetch k+1
            if (k < 6) {
                const int nn = tid + (k + 1) * 1024;
                if (nn < N_) {
                    q0 = mwp[(size_t)nn * 2];
                    q1 = mwp[(size_t)nn * 2 + 1];
                    qx = mbp[nn];
                }
            }

            const int n = tid + k * 1024;
            if (n < N_) {
                union { uint4 u; __half2 h[4]; } a0u, a1u;
                a0u.u = m0; a1u.u = m1;
                const int pxs[4] = {px.x, px.y, px.z, px.w};

                __half2 accA = __float2half2_rn(0.f);
                __half2 accB = __float2half2_rn(0.f);
#pragma unroll
                for (int l = 0; l < L_; l++) {
                    const int W = HWW[l];
                    const int base = LOFF[l] + pxs[l];
                    const __half2 wp0 = (l < 2) ? a0u.h[(l & 1) * 2]     : a1u.h[(l & 1) * 2];
                    const __half2 wp1 = (l < 2) ? a0u.h[(l & 1) * 2 + 1] : a1u.h[(l & 1) * 2 + 1];
                    const __half2 w00 = __half2half2(__low2half(wp0));
                    const __half2 w01 = __half2half2(__high2half(wp0));
                    const __half2 w10 = __half2half2(__low2half(wp1));
                    const __half2 w11 = __half2half2(__high2half(wp1));
                    accA = __hfma2(w00, lds2[base],         accA);
                    accA = __hfma2(w01, lds2[base + 1],     accA);
                    accB = __hfma2(w10, lds2[base + W],     accB);
                    accB = __hfma2(w11, lds2[base + W + 1], accB);
                }
                acc[k] = __hadd2(acc[k], __hadd2(accA, accB));
            }

            if (k < 6) { m0 = q0; m1 = q1; px = qx; }
        }
    }

    __half2* pout = part2 + ((size_t)(b * CH_ + chalf) * SL2_ + slice) * N_;
#pragma unroll
    for (int k = 0; k < 7; k++) {
        const int n = tid + k * 1024;
        if (n < N_) pout[n] = acc[k];
    }
}

// ---------------------------------------------------------------------------
// Kernel 2 (legacy fallback, atomic path): unchanged 6-cam slice gather.
// ---------------------------------------------------------------------------
__global__ __launch_bounds__(1024) void gather_atomic(
    const float* __restrict__ f0, const float* __restrict__ f1,
    const float* __restrict__ f2, const float* __restrict__ f3,
    const uint4* __restrict__ meta_w, const int4* __restrict__ meta_b,
    float* __restrict__ agg)
{
    __shared__ __half2 lds2[HWT];

    const int tid = threadIdx.x;
    const int bid = blockIdx.x;
    const int slice = bid & 127;
    const int c = (bid >> 7) % C_;
    const int b = bid / (128 * C_);
    const int e0 = slice * 2;
    const int bc = b * C_ + c;

    const float* fs[4] = {f0, f1, f2, f3};

#pragma unroll
    for (int l = 0; l < L_; l++) {
        const int HW = HWH[l] * HWW[l];
        const float* s0 = fs[l] + (size_t)(bc * E_ + e0) * HW;
        const float* s1 = s0 + HW;
        const int quarter = HW >> 2;
        for (int q = tid; q < quarter; q += 1024) {
            int p = q * 4;
            float4 v0 = *(const float4*)(s0 + p);
            float4 v1 = *(const float4*)(s1 + p);
            union { uint4 u; __half2 h[4]; } pk;
            pk.h[0] = __floats2half2_rn(v0.x, v1.x);
            pk.h[1] = __floats2half2_rn(v0.y, v1.y);
            pk.h[2] = __floats2half2_rn(v0.z, v1.z);
            pk.h[3] = __floats2half2_rn(v0.w, v1.w);
            *(uint4*)&lds2[LOFF[l] + p] = pk.u;
        }
    }
    __syncthreads();

    const size_t mbase = (size_t)bc * N_;
    const uint4* mwp = meta_w + mbase * 2;
    const int4* mbp = meta_b + mbase;
    float* aggb = agg + (size_t)b * N_ * E_ + e0;

    for (int n = tid; n < N_; n += 1024) {
        uint4 m0 = mwp[(size_t)n * 2];
        uint4 m1 = mwp[(size_t)n * 2 + 1];
        int4 px = mbp[n];

        union { uint4 u; __half2 h[4]; } a0u, a1u;
        a0u.u = m0; a1u.u = m1;
        const int pxs[4] = {px.x, px.y, px.z, px.w};

        __half2 accA = __float2half2_rn(0.f);
        __half2 accB = __float2half2_rn(0.f);
#pragma unroll
        for (int l = 0; l < L_; l++) {
            const int W = HWW[l];
            const int base = LOFF[l] + pxs[l];
            const __half2 wp0 = (l < 2) ? a0u.h[(l & 1) * 2]     : a1u.h[(l & 1) * 2];
            const __half2 wp1 = (l < 2) ? a0u.h[(l & 1) * 2 + 1] : a1u.h[(l & 1) * 2 + 1];
            const __half2 w00 = __half2half2(__low2half(wp0));
            const __half2 w01 = __half2half2(__high2half(wp0));
            const __half2 w10 = __half2half2(__low2half(wp1));
            const __half2 w11 = __half2half2(__high2half(wp1));
            accA = __hfma2(w00, lds2[base],         accA);
            accA = __hfma2(w01, lds2[base + 1],     accA);
            accB = __hfma2(w10, lds2[base + W],     accB);
            accB = __hfma2(w11, lds2[base + W + 1], accB);
        }
        float2 af = __half22float2(__hadd2(accA, accB));
        if (af.x != 0.f || af.y != 0.f) {
            float* dst = aggb + (size_t)n * E_;
            atomicAdd(dst + 0, af.x);
            atomicAdd(dst + 1, af.y);
        }
    }
}

// ---------------------------------------------------------------------------
// Kernel 3 (main path): MFMA f16 epilogue, 128-point tiles / 1024 threads.
// sA staging now reduces 2 cam-half partials (was 6 cams).
// ---------------------------------------------------------------------------
#define SAS2 264   // sA row stride (halves)
#define WSS2 72    // wS row stride (halves)
#define KC 64      // k-chunk

__global__ __launch_bounds__(1024, 4) void gemm_mfma(
    const float* __restrict__ inst,
    const float* __restrict__ vp_w, const float* __restrict__ vp_b,
    const float* __restrict__ op_w, const float* __restrict__ op_b,
    const __half2* __restrict__ part2, float* __restrict__ out)
{
    __shared__ _Float16 sA[128 * SAS2];  // 67584 B
    __shared__ _Float16 wS[256 * WSS2];  // 36864 B

    const int tid = threadIdx.x;
    const int wave = tid >> 6;
    const int lane = tid & 63;
    const int mt = wave & 7;        // m-tile (16 points), 8 tiles
    const int nh = wave >> 3;       // col half (128 e)
    const int q = lane >> 4;        // quad
    const int col = lane & 15;

    const int p0 = blockIdx.x * 128;
    const int b = p0 / N_;                   // tile never crosses b (6400%128==0)
    const int nbase = p0 - b * N_;

    // ---- stage sA: reduce 2 cam-half partials, f32 acc -> f16 ----
    {
        const int p = tid & 127, sg = tid >> 7;   // 8 slice-groups
        const int n = nbase + p;
        for (int s = sg; s < SL2_; s += 8) {
            float2 fa = __half22float2(
                part2[((size_t)(b * CH_ + 0) * SL2_ + s) * N_ + n]);
            float2 fb = __half22float2(
                part2[((size_t)(b * CH_ + 1) * SL2_ + s) * N_ + n]);
            sA[p * SAS2 + s * 2 + 0] = (_Float16)(fa.x + fb.x);
            sA[p * SAS2 + s * 2 + 1] = (_Float16)(fa.y + fb.y);
        }
    }

    floatx4 acc[8];
#pragma unroll
    for (int nt = 0; nt < 8; nt++) acc[nt] = (floatx4)(0.f);

    // ---- GEMM1: tmp = agg @ vp_w^T ----
    for (int kc = 0; kc < 256 / KC; kc++) {
        __syncthreads();
        {   // stage vp_w chunk: 4 threads per e-row, 16 k f32 -> f16 each
            const int row = tid >> 2, qt = tid & 3;
            const float* src = vp_w + (size_t)row * 256 + kc * KC + qt * 16;
            _Float16* dst = &wS[row * WSS2 + qt * 16];
#pragma unroll
            for (int i = 0; i < 2; i++) {
                float4 v = *(const float4*)(src + i * 8);
                float4 u = *(const float4*)(src + i * 8 + 4);
                half8 h = {(_Float16)v.x, (_Float16)v.y, (_Float16)v.z, (_Float16)v.w,
                           (_Float16)u.x, (_Float16)u.y, (_Float16)u.z, (_Float16)u.w};
                *(half8*)(dst + i * 8) = h;
            }
        }
        __syncthreads();
#pragma unroll
        for (int ks = 0; ks < KC / 32; ks++) {
            half8 a = *(half8*)&sA[(mt * 16 + col) * SAS2 + kc * KC + ks * 32 + q * 8];
#pragma unroll
            for (int nt = 0; nt < 8; nt++) {
                half8 bf = *(half8*)&wS[(nh * 128 + nt * 16 + col) * WSS2 + ks * 32 + q * 8];
                acc[nt] = __builtin_amdgcn_mfma_f32_16x16x32_f16(a, bf, acc[nt], 0, 0, 0);
            }
        }
    }

    // ---- middle: tmp = acc + vp_b + inst -> sA IN PLACE; reset acc ----
    __syncthreads();   // all GEMM1 reads of sA must complete before overwrite
#pragma unroll
    for (int nt = 0; nt < 8; nt++) {
        const int e = nh * 128 + nt * 16 + col;
        const float bv = vp_b[e];
#pragma unroll
        for (int r = 0; r < 4; r++) {
            const int p = mt * 16 + q * 4 + r;
            float t = acc[nt][r] + bv + inst[(size_t)(p0 + p) * E_ + e];
            sA[p * SAS2 + e] = (_Float16)t;
        }
        acc[nt] = (floatx4)(0.f);
    }

    // ---- GEMM2: out = tmp @ op_w^T ----
    for (int kc = 0; kc < 256 / KC; kc++) {
        __syncthreads();
        {
            const int row = tid >> 2, qt = tid & 3;
            const float* src = op_w + (size_t)row * 256 + kc * KC + qt * 16;
            _Float16* dst = &wS[row * WSS2 + qt * 16];
#pragma unroll
            for (int i = 0; i < 2; i++) {
                float4 v = *(const float4*)(src + i * 8);
                float4 u = *(const float4*)(src + i * 8 + 4);
                half8 h = {(_Float16)v.x, (_Float16)v.y, (_Float16)v.z, (_Float16)v.w,
                           (_Float16)u.x, (_Float16)u.y, (_Float16)u.z, (_Float16)u.w};
                *(half8*)(dst + i * 8) = h;
            }
        }
        __syncthreads();
#pragma unroll
        for (int ks = 0; ks < KC / 32; ks++) {
            half8 a = *(half8*)&sA[(mt * 16 + col) * SAS2 + kc * KC + ks * 32 + q * 8];
#pragma unroll
            for (int nt = 0; nt < 8; nt++) {
                half8 bf = *(half8*)&wS[(nh * 128 + nt * 16 + col) * WSS2 + ks * 32 + q * 8];
                acc[nt] = __builtin_amdgcn_mfma_f32_16x16x32_f16(a, bf, acc[nt], 0, 0, 0);
            }
        }
    }

    // ---- store out + op_b ----
#pragma unroll
    for (int nt = 0; nt < 8; nt++) {
        const int e = nh * 128 + nt * 16 + col;
        const float ob = op_b[e];
#pragma unroll
        for (int r = 0; r < 4; r++) {
            const int p = mt * 16 + q * 4 + r;
            out[(size_t)(p0 + p) * E_ + e] = acc[nt][r] + ob;
        }
    }
}

// ---------------------------------------------------------------------------
// Fallback VALU epilogue (atomic path). (unchanged)
// ---------------------------------------------------------------------------
#define PT 32
#define SAS 264
#define WSS 36

__global__ __launch_bounds__(256) void gemm_valu(
    const float* __restrict__ inst,
    const float* __restrict__ vp_w, const float* __restrict__ vp_b,
    const float* __restrict__ op_w, const float* __restrict__ op_b,
    float* __restrict__ io)
{
    __shared__ __align__(16) float sA[PT * SAS];
    __shared__ __align__(16) float wS[256 * WSS];

    const int tid = threadIdx.x;
    const int eg = tid & 31;
    const int pg = tid >> 5;
    const int p0 = blockIdx.x * PT;

#pragma unroll
    for (int r = 0; r < PT; r++)
        sA[r * SAS + tid] = io[(size_t)(p0 + r) * E_ + tid];
    __syncthreads();

    float acc[4][8];
#pragma unroll
    for (int j = 0; j < 4; j++)
#pragma unroll
        for (int i = 0; i < 8; i++) acc[j][i] = 0.f;

    for (int k0 = 0; k0 < 256; k0 += 32) {
        __syncthreads();
#pragma unroll
        for (int r = 0; r < 32; r++) {
            int lin = r * 256 + tid;
            int e = lin >> 5, kk = lin & 31;
            wS[e * WSS + kk] = vp_w[(size_t)e * 256 + k0 + kk];
        }
        __syncthreads();
#pragma unroll
        for (int kk = 0; kk < 32; kk += 4) {
            float4 wv4[8], av4[4];
#pragma unroll
            for (int i = 0; i < 8; i++)
                wv4[i] = *(const float4*)&wS[(eg + 32 * i) * WSS + kk];
#pragma unroll
            for (int j = 0; j < 4; j++)
                av4[j] = *(const float4*)&sA[(pg * 4 + j) * SAS + k0 + kk];
#pragma unroll
            for (int j = 0; j < 4; j++)
#pragma unroll
                for (int i = 0; i < 8; i++)
                    acc[j][i] += av4[j].x * wv4[i].x + av4[j].y * wv4[i].y
                               + av4[j].z * wv4[i].z + av4[j].w * wv4[i].w;
        }
    }

    __syncthreads();
#pragma unroll
    for (int j = 0; j < 4; j++) {
        int p = pg * 4 + j;
#pragma unroll
        for (int i = 0; i < 8; i++) {
            int e = eg + 32 * i;
            float t = acc[j][i] + vp_b[e] + inst[(size_t)(p0 + p) * E_ + e];
            sA[p * SAS + e] = t;
            acc[j][i] = 0.f;
        }
    }

    for (int k0 = 0; k0 < 256; k0 += 32) {
        __syncthreads();
#pragma unroll
        for (int r = 0; r < 32; r++) {
            int lin = r * 256 + tid;
            int e = lin >> 5, kk = lin & 31;
            wS[e * WSS + kk] = op_w[(size_t)e * 256 + k0 + kk];
        }
        __syncthreads();
#pragma unroll
        for (int kk = 0; kk < 32; kk += 4) {
            float4 wv4[8], av4[4];
#pragma unroll
            for (int i = 0; i < 8; i++)
                wv4[i] = *(const float4*)&wS[(eg + 32 * i) * WSS + kk];
#pragma unroll
            for (int j = 0; j < 4; j++)
                av4[j] = *(const float4*)&sA[(pg * 4 + j) * SAS + k0 + kk];
#pragma unroll
            for (int j = 0; j < 4; j++)
#pragma unroll
                for (int i = 0; i < 8; i++)
                    acc[j][i] += av4[j].x * wv4[i].x + av4[j].y * wv4[i].y
                               + av4[j].z * wv4[i].z + av4[j].w * wv4[i].w;
        }
    }

#pragma unroll
    for (int j = 0; j < 4; j++) {
        int p = pg * 4 + j;
#pragma unroll
        for (int i = 0; i < 8; i++) {
            int e = eg + 32 * i;
            io[(size_t)(p0 + p) * E_ + e] = acc[j][i] + op_b[e];
        }
    }
}

// ---------------------------------------------------------------------------
extern "C" void kernel_launch(void* const* d_in, const int* in_sizes, int n_in,
                              void* d_out, int out_size, void* d_ws, size_t ws_size,
                              hipStream_t stream)
{
    const float* inst   = (const float*)d_in[0];
    const float* anchor = (const float*)d_in[1];
    const float* proj   = (const float*)d_in[2];
    const float* f0     = (const float*)d_in[3];
    const float* f1     = (const float*)d_in[4];
    const float* f2     = (const float*)d_in[5];
    const float* f3     = (const float*)d_in[6];
    const float* attn_w = (const float*)d_in[7];
    const float* attn_b = (const float*)d_in[8];
    const float* vp_w   = (const float*)d_in[9];
    const float* vp_b   = (const float*)d_in[10];
    const float* op_w   = (const float*)d_in[11];
    const float* op_b   = (const float*)d_in[12];
    float* out = (float*)d_out;

    // ws layout: meta_w (32 B/pt) | meta_b (16 B/pt) | partials (fp16, 13.1 MB)
    const size_t NPT = (size_t)B_ * C_ * N_;
    uint4* meta_w = (uint4*)d_ws;
    int4* meta_b = (int4*)((char*)d_ws + NPT * 32);
    __half2* part2 = (__half2*)((char*)d_ws + NPT * 48);
    const size_t part2_bytes = (size_t)B_ * CH_ * SL2_ * N_ * sizeof(__half2);
    const size_t need = NPT * 48 + part2_bytes;

    prep_kernel<<<(B_ * N_) / 256, 256, 0, stream>>>(
        inst, anchor, proj, attn_w, attn_b, meta_w, meta_b);

    if (ws_size >= need) {
        gather3<<<B_ * CH_ * SL2_, 1024, 0, stream>>>(
            f0, f1, f2, f3, meta_w, meta_b, part2);
        gemm_mfma<<<(B_ * N_) / 128, 1024, 0, stream>>>(
            inst, vp_w, vp_b, op_w, op_b, part2, out);
    } else {
        hipMemsetAsync(d_out, 0, (size_t)out_size * sizeof(float), stream);
        gather_atomic<<<B_ * C_ * SL2_, 1024, 0, stream>>>(
            f0, f1, f2, f3, meta_w, meta_b, out);
        gemm_valu<<<(B_ * N_) / PT, 256, 0, stream>>>(
            inst, vp_w, vp_b, op_w, op_b, out);
    }
}